// Round 1
// baseline (1375.394 us; speedup 1.0000x reference)
//
#include <hip/hip_runtime.h>
#include <math.h>

// RelationalKENN: two-stage clause enhancer.
// Stage 1 (nodes): u = unary + KE(unary, U_IDX=[i,i+1,i+2], sgn=[-1,1,1], w)
// Stage 2 (edges): clause i uses (-u1[i], b[i&3], u2[i]); softmax; scatter:
//   out_u[i1][i] += -w*p0 ; out_u[i2][i] += w*p2 ; out_b[e][i&3] += w*p1
// Only u columns 0..7 are ever gathered -> pack u_lo[n_nodes*8] in workspace.

#define NU 16
#define NC 8

__global__ void unary_enhance_kernel(const float* __restrict__ unary,
                                     const float* __restrict__ ucw,
                                     float* __restrict__ out_u,   // [n_nodes*16]
                                     float* __restrict__ u_lo,    // [n_nodes*8]
                                     int n_nodes) {
    int n = blockIdx.x * blockDim.x + threadIdx.x;
    if (n >= n_nodes) return;

    float x[NU];
    const float4* src = (const float4*)(unary + (size_t)n * NU);
#pragma unroll
    for (int j = 0; j < 4; ++j) {
        float4 v = src[j];
        x[4*j+0] = v.x; x[4*j+1] = v.y; x[4*j+2] = v.z; x[4*j+3] = v.w;
    }

    float dlt[NU];
#pragma unroll
    for (int j = 0; j < NU; ++j) dlt[j] = 0.0f;

#pragma unroll
    for (int i = 0; i < NC; ++i) {
        float w = ucw[i];
        float a = -x[i], b = x[i+1], c = x[i+2];
        float m = fmaxf(a, fmaxf(b, c));
        float e0 = __expf(a - m);
        float e1 = __expf(b - m);
        float e2 = __expf(c - m);
        float inv = 1.0f / (e0 + e1 + e2);
        dlt[i]   -= w * e0 * inv;
        dlt[i+1] += w * e1 * inv;
        dlt[i+2] += w * e2 * inv;
    }

    float u[NU];
#pragma unroll
    for (int j = 0; j < NU; ++j) u[j] = x[j] + dlt[j];

    float4* dst = (float4*)(out_u + (size_t)n * NU);
#pragma unroll
    for (int j = 0; j < 4; ++j) {
        float4 v; v.x = u[4*j+0]; v.y = u[4*j+1]; v.z = u[4*j+2]; v.w = u[4*j+3];
        dst[j] = v;
    }
    // packed first-8-columns snapshot for the edge-stage gather
    float4* lo = (float4*)(u_lo + (size_t)n * 8);
    float4 l0; l0.x = u[0]; l0.y = u[1]; l0.z = u[2]; l0.w = u[3];
    float4 l1; l1.x = u[4]; l1.y = u[5]; l1.z = u[6]; l1.w = u[7];
    lo[0] = l0; lo[1] = l1;
}

__global__ void edge_enhance_kernel(const float* __restrict__ binary,
                                    const float* __restrict__ bcw,
                                    const int* __restrict__ index1,
                                    const int* __restrict__ index2,
                                    const float* __restrict__ u_lo,
                                    float* __restrict__ out_u,   // [n_nodes*16], atomically updated
                                    float* __restrict__ out_b,   // [n_edges*4]
                                    int n_edges) {
    int e = blockIdx.x * blockDim.x + threadIdx.x;
    if (e >= n_edges) return;

    int i1 = index1[e];
    int i2 = index2[e];

    float4 bv = ((const float4*)binary)[e];
    float b[4] = {bv.x, bv.y, bv.z, bv.w};

    float u1[8], u2[8];
    {
        const float4* p1 = (const float4*)(u_lo + (size_t)i1 * 8);
        float4 a0 = p1[0], a1 = p1[1];
        u1[0]=a0.x; u1[1]=a0.y; u1[2]=a0.z; u1[3]=a0.w;
        u1[4]=a1.x; u1[5]=a1.y; u1[6]=a1.z; u1[7]=a1.w;
        const float4* p2 = (const float4*)(u_lo + (size_t)i2 * 8);
        float4 c0 = p2[0], c1 = p2[1];
        u2[0]=c0.x; u2[1]=c0.y; u2[2]=c0.z; u2[3]=c0.w;
        u2[4]=c1.x; u2[5]=c1.y; u2[6]=c1.z; u2[7]=c1.w;
    }

    float d1[8], d2[8];
    float dbp[4] = {0.0f, 0.0f, 0.0f, 0.0f};

#pragma unroll
    for (int i = 0; i < NC; ++i) {
        float w = bcw[i];
        float a = -u1[i];
        float bb = b[i & 3];
        float c = u2[i];
        float m = fmaxf(a, fmaxf(bb, c));
        float e0 = __expf(a - m);
        float e1 = __expf(bb - m);
        float e2 = __expf(c - m);
        float inv = 1.0f / (e0 + e1 + e2);
        d1[i] = -w * e0 * inv;
        d2[i] =  w * e2 * inv;
        dbp[i & 3] += w * e1 * inv;
    }

    float* r1 = out_u + (size_t)i1 * NU;
#pragma unroll
    for (int i = 0; i < NC; ++i) atomicAdd(r1 + i, d1[i]);
    float* r2 = out_u + (size_t)i2 * NU;
#pragma unroll
    for (int i = 0; i < NC; ++i) atomicAdd(r2 + i, d2[i]);

    float4 ob;
    ob.x = b[0] + dbp[0];
    ob.y = b[1] + dbp[1];
    ob.z = b[2] + dbp[2];
    ob.w = b[3] + dbp[3];
    ((float4*)out_b)[e] = ob;
}

extern "C" void kernel_launch(void* const* d_in, const int* in_sizes, int n_in,
                              void* d_out, int out_size, void* d_ws, size_t ws_size,
                              hipStream_t stream) {
    const float* unary  = (const float*)d_in[0];
    const float* binary = (const float*)d_in[1];
    const float* ucw    = (const float*)d_in[2];
    const float* bcw    = (const float*)d_in[3];
    const int*   index1 = (const int*)d_in[4];
    const int*   index2 = (const int*)d_in[5];

    int n_nodes = in_sizes[0] / NU;
    int n_edges = in_sizes[4];

    float* out_u = (float*)d_out;                   // n_nodes*16
    float* out_b = out_u + (size_t)n_nodes * NU;    // n_edges*4
    float* u_lo  = (float*)d_ws;                    // n_nodes*8 floats = 3.2 MB

    int tb = 256;
    unary_enhance_kernel<<<(n_nodes + tb - 1) / tb, tb, 0, stream>>>(
        unary, ucw, out_u, u_lo, n_nodes);
    edge_enhance_kernel<<<(n_edges + tb - 1) / tb, tb, 0, stream>>>(
        binary, bcw, index1, index2, u_lo, out_u, out_b, n_edges);
}